// Round 4
// baseline (860.663 us; speedup 1.0000x reference)
//
#include <hip/hip_runtime.h>
#include <cmath>

#define B_ 4
#define N_ 4096
#define NF_ 8192
#define K_ 512
#define C_ 128
#define L_ 4
#define FCD_ 128
#define SPLIT_ 16

typedef _Float16 f16x8 __attribute__((ext_vector_type(8)));
typedef _Float16 f16x4 __attribute__((ext_vector_type(4)));
typedef float f32x4 __attribute__((ext_vector_type(4)));

#define MFMA16(a, b, c) __builtin_amdgcn_mfma_f32_16x16x32_f16((a), (b), (c), 0, 0, 0)

static const float SPLIT_SCALE = 2048.0f;      // 2^11
static const float INV_SPLIT_SCALE = 1.0f / 2048.0f;

// ---- workspace layout (float offsets; f16 arrays use count/2 floats) ----
static const size_t SZ_H   = (size_t)B_ * C_ * N_;       // fp32
static const size_t SZ_HS  = (size_t)B_ * C_ * N_ / 2;   // f16 split
static const size_t SZ_FS  = (size_t)B_ * C_ * K_ / 2;   // f16 split of fch/fsh
static const size_t SZ_CW  = (size_t)L_ * C_ * C_ / 2;   // f16 split conv_w
static const size_t SZ_W1  = (size_t)C_ * FCD_ / 2;      // f16 split fc1_w^T

static const size_t H_OFF    = 0;
static const size_t H2_OFF   = H_OFF + SZ_H;
static const size_t HAH_OFF  = H2_OFF + SZ_H;
static const size_t HAL_OFF  = HAH_OFF + SZ_HS;
static const size_t HTH_OFF  = HAL_OFF + SZ_HS;
static const size_t HTL_OFF  = HTH_OFF + SZ_HS;
static const size_t WQN_OFF  = HTL_OFF + SZ_HS;                  // B*N fp32
static const size_t GXY_OFF  = WQN_OFF + (size_t)B_ * N_;        // B*N*2 fp32 (gx,gy)
static const size_t XCH_OFF  = GXY_OFF + (size_t)B_ * N_ * 2;    // B*C*K fp32
static const size_t XSH_OFF  = XCH_OFF + (size_t)B_ * C_ * K_;
static const size_t FCHH_OFF = XSH_OFF + (size_t)B_ * C_ * K_;
static const size_t FCHL_OFF = FCHH_OFF + SZ_FS;
static const size_t FSHH_OFF = FCHL_OFF + SZ_FS;
static const size_t FSHL_OFF = FSHH_OFF + SZ_FS;
static const size_t CWH_OFF  = FSHL_OFF + SZ_FS;
static const size_t CWL_OFF  = CWH_OFF + SZ_CW;
static const size_t X0_OFF   = CWL_OFF + SZ_CW;                  // B*C
static const size_t F0_OFF   = X0_OFF + (size_t)B_ * C_;
static const size_t XCP_OFF  = F0_OFF + (size_t)B_ * C_;         // SPLIT*B*C*K
static const size_t XSP_OFF  = XCP_OFF + (size_t)SPLIT_ * B_ * C_ * K_;
static const size_t W1TH_OFF = XSP_OFF + (size_t)SPLIT_ * B_ * C_ * K_;
static const size_t W1TL_OFF = W1TH_OFF + SZ_W1;
static const size_t TAB_OFF  = W1TL_OFF + SZ_W1;                 // B*68*N fp32 (SoA planes)
// end ~= 19.1M floats ~= 76 MB

__device__ __forceinline__ float gelu_exact(float v) {
    return v * 0.5f * (1.0f + erff(v * 0.70710678118654752440f));
}

__device__ __forceinline__ void fsplit(float v, _Float16& hi, _Float16& lo) {
    hi = (_Float16)v;
    lo = (_Float16)((v - (float)hi) * SPLIT_SCALE);
}

// h[b,c,n] = fc0(x);  wqn[b,n] = wq[b,ind[n]] * N;  gxy[b,n] = grid[b,ind[n],0:2]
__global__ void prep_kernel(const float* __restrict__ x, const float* __restrict__ xf,
                            const int* __restrict__ ind, const float* __restrict__ fc0_w,
                            const float* __restrict__ fc0_b, float* __restrict__ h,
                            float* __restrict__ wqn, float* __restrict__ gxy) {
    int n = blockIdx.x * 256 + threadIdx.x;
    int c = blockIdx.y;
    int b = blockIdx.z;
    const float* xp = x + ((size_t)b * N_ + n) * 3;
    float acc = fc0_b[c] + xp[0] * fc0_w[0 * C_ + c] + xp[1] * fc0_w[1 * C_ + c]
              + xp[2] * fc0_w[2 * C_ + c];
    h[((size_t)b * C_ + c) * N_ + n] = acc;
    if (c == 0) {
        int g = ind[n];
        const float* xfp = xf + ((size_t)b * NF_ + g) * 4;
        wqn[b * N_ + n] = xfp[2] * (float)N_;
        gxy[((size_t)b * N_ + n) * 2 + 0] = xfp[0];
        gxy[((size_t)b * N_ + n) * 2 + 1] = xfp[1];
    }
}

// angle tables, SoA planes: tab[(b*68 + plane)*N + n]
// planes 0..16: cos(gx*i), 17..33: sin(gx*i), 34..50: cos(gy*i), 51..67: sin(gy*i)
__global__ void tab_kernel(const float* __restrict__ gxy, float* __restrict__ tab) {
    int n = blockIdx.x * 256 + threadIdx.x;
    int b = blockIdx.y;
    float gx = gxy[((size_t)b * N_ + n) * 2 + 0];
    float gy = gxy[((size_t)b * N_ + n) * 2 + 1];
    float* base = tab + (size_t)b * 68 * N_ + n;
    for (int i = 0; i < 17; ++i) {
        float s, c;
        sincosf(gx * (float)i, &s, &c);
        base[(size_t)i * N_] = c;
        base[(size_t)(17 + i) * N_] = s;
        sincosf(gy * (float)i, &s, &c);
        base[(size_t)(34 + i) * N_] = c;
        base[(size_t)(51 + i) * N_] = s;
    }
}

// conv_w -> f16 hi/lo (all layers)
__global__ void conv_split(const float* __restrict__ conv_w, _Float16* __restrict__ cwh,
                           _Float16* __restrict__ cwl) {
    int t = blockIdx.x * 256 + threadIdx.x;
    _Float16 hi, lo;
    fsplit(conv_w[t], hi, lo);
    cwh[t] = hi; cwl[t] = lo;
}

// fc1_w^T -> f16 hi/lo  (w1t[j][c] = fc1_w[c][j])
__global__ void w1_split(const float* __restrict__ fc1_w, _Float16* __restrict__ w1th,
                         _Float16* __restrict__ w1tl) {
    int t = blockIdx.x * 256 + threadIdx.x;   // t = j*C_ + c
    int j = t >> 7, c = t & (C_ - 1);
    _Float16 hi, lo;
    fsplit(fc1_w[c * FCD_ + j], hi, lo);
    w1th[t] = hi; w1tl[t] = lo;
}

__device__ __forceinline__ unsigned int pack2(_Float16 a, _Float16 b) {
    union { _Float16 f[2]; unsigned int u; } x;
    x.f[0] = a; x.f[1] = b;
    return x.u;
}

__device__ __forceinline__ void unpack2(unsigned int v, _Float16& a, _Float16& b) {
    union { _Float16 f[2]; unsigned int u; } x;
    x.u = v;
    a = x.f[0]; b = x.f[1];
}

// per-layer: hA = split(h*wqn) [c][n];  hT = split(h) [n][c]
__global__ __launch_bounds__(256) void split_h(const float* __restrict__ h,
        const float* __restrict__ wqn, _Float16* __restrict__ hah,
        _Float16* __restrict__ hal, _Float16* __restrict__ hth,
        _Float16* __restrict__ htl) {
    __shared__ unsigned int pk[64][65];
    int tid = threadIdx.x;
    int n0 = blockIdx.x * 64, c0 = blockIdx.y * 64, b = blockIdx.z;
    int col = tid & 63, row4 = tid >> 6;
    for (int r = row4; r < 64; r += 4) {
        int c = c0 + r, n = n0 + col;
        float v = h[((size_t)b * C_ + c) * N_ + n];
        _Float16 ph, pl;
        fsplit(v, ph, pl);
        pk[r][col] = pack2(ph, pl);
        float a = v * wqn[b * N_ + n];
        _Float16 ah, al;
        fsplit(a, ah, al);
        size_t o = ((size_t)b * C_ + c) * N_ + n;
        hah[o] = ah; hal[o] = al;
    }
    __syncthreads();
    for (int r = row4; r < 64; r += 4) {
        int n = n0 + r, c = c0 + col;
        _Float16 ph, pl;
        unpack2(pk[col][r], ph, pl);
        size_t o = ((size_t)b * N_ + n) * C_ + c;
        hth[o] = ph; htl[o] = pl;
    }
}

// fwd MFMA with table-based LDS bases:
// xcp[p,b,c,k] = sum_{n in chunk p} (h*wqn)*cos ; xsp = -sum (h*wqn)*sin
// grid (K/32, SPLIT, B) = 1024 blocks; block: 128c x 32k; wave: 32c x 32k (2x2 tiles)
__global__ __launch_bounds__(256) void fwd_mfma(const _Float16* __restrict__ hah,
        const _Float16* __restrict__ hal, const float* __restrict__ tab,
        const float* __restrict__ modes, float* __restrict__ xcp,
        float* __restrict__ xsp) {
    __shared__ __align__(16) _Float16 tCH[2][32][40];
    __shared__ __align__(16) _Float16 tCL[2][32][40];
    __shared__ __align__(16) _Float16 tSH[2][32][40];
    __shared__ __align__(16) _Float16 tSL[2][32][40];
    int tid = threadIdx.x;
    int w = tid >> 6, lane = tid & 63, l15 = lane & 15, q = lane >> 4;
    int k0g = blockIdx.x * 32, p = blockIdx.y, b = blockIdx.z;
    int cstrip = w * 32;
    // per-thread fixed k for tile compute
    int kk = tid & 31, ng = tid >> 5;   // ng in 0..7, covers nn = ng*4+j
    float mx = modes[(k0g + kk) * 2 + 0];
    float my = modes[(k0g + kk) * 2 + 1];
    int ia = (int)fabsf(mx), ib = (int)fabsf(my);
    float sgnA = mx < 0.f ? -1.f : 1.f;
    float sgnB = my < 0.f ? -1.f : 1.f;
    float sgnAB = sgnA * sgnB;
    const float* pAc = tab + ((size_t)b * 68 + ia) * N_;
    const float* pAs = tab + ((size_t)b * 68 + 17 + ia) * N_;
    const float* pBc = tab + ((size_t)b * 68 + 34 + ib) * N_;
    const float* pBs = tab + ((size_t)b * 68 + 51 + ib) * N_;

    size_t arow[2];
    arow[0] = ((size_t)b * C_ + cstrip + l15) * N_;
    arow[1] = arow[0] + (size_t)16 * N_;
    f32x4 z = {0.f, 0.f, 0.f, 0.f};
    f32x4 aC1[2][2], aC2[2][2], aS1[2][2], aS2[2][2];
    for (int i = 0; i < 2; ++i)
        for (int j = 0; j < 2; ++j) {
            aC1[i][j] = z; aC2[i][j] = z; aS1[i][j] = z; aS2[i][j] = z;
        }

#define FWD_TILE(ITER, BUF) do {                                             \
        int n0_ = p * (N_ / SPLIT_) + (ITER) * 32 + ng * 4;                  \
        f32x4 cA_ = *(const f32x4*)(pAc + n0_);                              \
        f32x4 sA_ = *(const f32x4*)(pAs + n0_);                              \
        f32x4 cB_ = *(const f32x4*)(pBc + n0_);                              \
        f32x4 sB_ = *(const f32x4*)(pBs + n0_);                              \
        f16x4 vch_, vcl_, vsh_, vsl_;                                        \
        for (int j_ = 0; j_ < 4; ++j_) {                                     \
            float c_ = cA_[j_] * cB_[j_] - sgnAB * (sA_[j_] * sB_[j_]);      \
            float s_ = sgnA * sA_[j_] * cB_[j_] + sgnB * cA_[j_] * sB_[j_];  \
            _Float16 h_, lo_;                                                \
            fsplit(c_, h_, lo_); vch_[j_] = h_; vcl_[j_] = lo_;              \
            fsplit(s_, h_, lo_); vsh_[j_] = h_; vsl_[j_] = lo_;              \
        }                                                                    \
        *(f16x4*)&tCH[BUF][kk][ng * 4] = vch_;                               \
        *(f16x4*)&tCL[BUF][kk][ng * 4] = vcl_;                               \
        *(f16x4*)&tSH[BUF][kk][ng * 4] = vsh_;                               \
        *(f16x4*)&tSL[BUF][kk][ng * 4] = vsl_;                               \
    } while (0)

    FWD_TILE(0, 0);
    const int NIT = (N_ / SPLIT_) / 32;   // 8
    for (int it = 0; it < NIT; ++it) {
        __syncthreads();
        int cur = it & 1;
        int off = p * (N_ / SPLIT_) + it * 32 + q * 8;
        f16x8 ah[2], al[2];
        for (int mt = 0; mt < 2; ++mt) {
            ah[mt] = *(const f16x8*)(hah + arow[mt] + off);
            al[mt] = *(const f16x8*)(hal + arow[mt] + off);
        }
        f16x8 bch[2], bcl[2], bsh[2], bsl[2];
        for (int kt = 0; kt < 2; ++kt) {
            int r = kt * 16 + l15;
            bch[kt] = *(const f16x8*)&tCH[cur][r][q * 8];
            bcl[kt] = *(const f16x8*)&tCL[cur][r][q * 8];
            bsh[kt] = *(const f16x8*)&tSH[cur][r][q * 8];
            bsl[kt] = *(const f16x8*)&tSL[cur][r][q * 8];
        }
        if (it + 1 < NIT) FWD_TILE(it + 1, cur ^ 1);
        for (int mt = 0; mt < 2; ++mt)
            for (int kt = 0; kt < 2; ++kt) {
                aC1[mt][kt] = MFMA16(ah[mt], bch[kt], aC1[mt][kt]);
                aC2[mt][kt] = MFMA16(ah[mt], bcl[kt], aC2[mt][kt]);
                aC2[mt][kt] = MFMA16(al[mt], bch[kt], aC2[mt][kt]);
                aS1[mt][kt] = MFMA16(ah[mt], bsh[kt], aS1[mt][kt]);
                aS2[mt][kt] = MFMA16(ah[mt], bsl[kt], aS2[mt][kt]);
                aS2[mt][kt] = MFMA16(al[mt], bsh[kt], aS2[mt][kt]);
            }
    }
#undef FWD_TILE
    size_t pb = (size_t)p * B_ + b;
    for (int mt = 0; mt < 2; ++mt)
        for (int kt = 0; kt < 2; ++kt)
            for (int r = 0; r < 4; ++r) {
                int c = cstrip + mt * 16 + q * 4 + r;
                int k = k0g + kt * 16 + l15;
                size_t o = (pb * C_ + c) * K_ + k;
                xcp[o] = aC1[mt][kt][r] + aC2[mt][kt][r] * INV_SPLIT_SCALE;
                xsp[o] = -(aS1[mt][kt][r] + aS2[mt][kt][r] * INV_SPLIT_SCALE);
            }
}

__global__ void red_kernel(const float* __restrict__ xcp, const float* __restrict__ xsp,
                           float* __restrict__ xch, float* __restrict__ xsh) {
    int t = blockIdx.x * 256 + threadIdx.x;
    const int BCK = B_ * C_ * K_;
    float a = 0.f, s = 0.f;
    for (int p = 0; p < SPLIT_; ++p) {
        a += xcp[(size_t)p * BCK + t];
        s += xsp[(size_t)p * BCK + t];
    }
    xch[t] = a; xsh[t] = s;
}

// x0h[b,c] = sum_n h*wqn
__global__ void x0_kernel(const float* __restrict__ h, const float* __restrict__ wqn,
                          float* __restrict__ x0h) {
    int c = blockIdx.x, b = blockIdx.y;
    int tid = threadIdx.x;
    const float* hp = h + ((size_t)b * C_ + c) * N_;
    const float* wq = wqn + b * N_;
    float a = 0.f;
    for (int n = tid; n < N_; n += 256) a += hp[n] * wq[n];
    __shared__ float red[4];
    for (int off = 32; off; off >>= 1) a += __shfl_down(a, off, 64);
    if ((tid & 63) == 0) red[tid >> 6] = a;
    __syncthreads();
    if (tid == 0) x0h[b * C_ + c] = red[0] + red[1] + red[2] + red[3];
}

// f0h[b,o] = (sum_i x0h[b,i]*w0[l,i,o]) / NF
__global__ void f0_kernel(const float* __restrict__ x0h, const float* __restrict__ w0,
                          int l, float* __restrict__ f0h) {
    int o = threadIdx.x, b = blockIdx.x;
    const float* w = w0 + (size_t)l * C_ * C_;
    float a = 0.f;
    for (int i = 0; i < C_; ++i) a += x0h[b * C_ + i] * w[i * C_ + o];
    f0h[b * C_ + o] = a * (1.0f / NF_);
}

// fch' = (2/NF)*sum_i(xch*wc - xsh*ws); fsh' = (2/NF)*sum_i(xsh*wc + xch*ws)
// writes f16 splits directly; fsh split is NEGATED (inv only accumulates +)
__global__ __launch_bounds__(256) void mix_kernel(const float* __restrict__ xch,
        const float* __restrict__ xsh, const float* __restrict__ wc,
        const float* __restrict__ ws, int l, _Float16* __restrict__ fchh,
        _Float16* __restrict__ fchl, _Float16* __restrict__ fshh,
        _Float16* __restrict__ fshl) {
    __shared__ float red[512 * 5];
    int tid = threadIdx.x;
    int lane = tid & 63;
    int g = tid >> 6;
    int k = blockIdx.x * 64 + lane;
    int o = blockIdx.y;
    const float* wcb = wc + ((size_t)l * C_ * C_ + o) * K_ + k;
    const float* wsb = ws + ((size_t)l * C_ * C_ + o) * K_ + k;
    float fc[4] = {0, 0, 0, 0}, fs[4] = {0, 0, 0, 0};
    int i0 = g * 32;
#pragma unroll 4
    for (int ii = 0; ii < 32; ++ii) {
        int i = i0 + ii;
        float wci = wcb[(size_t)i * (C_ * K_)];
        float wsi = wsb[(size_t)i * (C_ * K_)];
#pragma unroll
        for (int b = 0; b < 4; ++b) {
            float xc = xch[((size_t)b * C_ + i) * K_ + k];
            float xs = xsh[((size_t)b * C_ + i) * K_ + k];
            fc[b] += xc * wci - xs * wsi;
            fs[b] += xs * wci + xc * wsi;
        }
    }
#pragma unroll
    for (int b = 0; b < 4; ++b) {
        red[((b * 2 + 0) * 64 + lane) * 5 + g] = fc[b];
        red[((b * 2 + 1) * 64 + lane) * 5 + g] = fs[b];
    }
    __syncthreads();
    const float sc = 2.0f / NF_;
    for (int v = tid; v < 512; v += 256) {
        float sum = (red[v * 5 + 0] + red[v * 5 + 1] + red[v * 5 + 2] + red[v * 5 + 3]) * sc;
        int lane2 = v & 63;
        int bs = v >> 6;
        int b = bs >> 1, s = bs & 1;
        size_t idx = ((size_t)b * C_ + o) * K_ + blockIdx.x * 64 + lane2;
        _Float16 hi, lo;
        if (s == 0) {
            fsplit(sum, hi, lo);
            fchh[idx] = hi; fchl[idx] = lo;
        } else {
            fsplit(-sum, hi, lo);
            fshh[idx] = hi; fshl[idx] = lo;
        }
    }
}

// inv MFMA with table-based LDS bases:
// hnext[b,c,n] = gelu?( sum_k fch*cos + fshN*sin + sum_i cw[c,i]*h[i,n] + f0h + conv_b )
// grid (N/32, B) = 512 blocks; block 128c x 32n; wave 32c x 32n (2x2 tiles)
__global__ __launch_bounds__(256) void inv_mfma(const _Float16* __restrict__ fchh,
        const _Float16* __restrict__ fchl, const _Float16* __restrict__ fshh,
        const _Float16* __restrict__ fshl, const float* __restrict__ tab,
        const float* __restrict__ modes, const _Float16* __restrict__ cwh,
        const _Float16* __restrict__ cwl, const _Float16* __restrict__ hth,
        const _Float16* __restrict__ htl, const float* __restrict__ f0h,
        const float* __restrict__ conv_b, int l, int last, float* __restrict__ hnext) {
    __shared__ __align__(16) _Float16 tCH[2][32][40];
    __shared__ __align__(16) _Float16 tCL[2][32][40];
    __shared__ __align__(16) _Float16 tSH[2][32][40];
    __shared__ __align__(16) _Float16 tSL[2][32][40];
    __shared__ float mx_s[K_], my_s[K_];
    int tid = threadIdx.x;
    int w = tid >> 6, lane = tid & 63, l15 = lane & 15, q = lane >> 4;
    int n0g = blockIdx.x * 32, b = blockIdx.y;
    int cstrip = w * 32;
    // preload all modes (K*2 floats)
    {
        float4 v = *(const float4*)(modes + tid * 4);
        mx_s[tid * 2 + 0] = v.x; my_s[tid * 2 + 0] = v.y;
        mx_s[tid * 2 + 1] = v.z; my_s[tid * 2 + 1] = v.w;
    }
    // per-thread fixed n for tile compute; its table columns are L1-resident
    int nn = tid & 31, kg = tid >> 5;   // kg in 0..7, covers kk = kg*4+j
    const float* rowb = tab + (size_t)b * 68 * N_ + (n0g + nn);

    size_t frow[2], nrow2[2], crow[2];
    frow[0] = ((size_t)b * C_ + cstrip + l15) * K_;
    frow[1] = frow[0] + (size_t)16 * K_;
    nrow2[0] = ((size_t)b * N_ + n0g + l15) * C_;
    nrow2[1] = nrow2[0] + (size_t)16 * C_;
    crow[0] = ((size_t)l * C_ + cstrip + l15) * C_;
    crow[1] = crow[0] + (size_t)16 * C_;
    f32x4 z = {0.f, 0.f, 0.f, 0.f};
    f32x4 a1[2][2], a2[2][2];
    for (int i = 0; i < 2; ++i)
        for (int j = 0; j < 2; ++j) { a1[i][j] = z; a2[i][j] = z; }

#define INV_TILE(KC, BUF) do {                                               \
        f16x4 vch_, vcl_, vsh_, vsl_;                                        \
        for (int j_ = 0; j_ < 4; ++j_) {                                     \
            int kk_ = (KC) + kg * 4 + j_;                                    \
            float mx_ = mx_s[kk_], my_ = my_s[kk_];                          \
            int ia_ = (int)fabsf(mx_), ib_ = (int)fabsf(my_);                \
            float sA_ = mx_ < 0.f ? -1.f : 1.f;                              \
            float sB_ = my_ < 0.f ? -1.f : 1.f;                              \
            float cA = rowb[(size_t)ia_ * N_];                               \
            float sA = rowb[(size_t)(17 + ia_) * N_];                        \
            float cB = rowb[(size_t)(34 + ib_) * N_];                        \
            float sB = rowb[(size_t)(51 + ib_) * N_];                        \
            float c_ = cA * cB - (sA_ * sB_) * (sA * sB);                    \
            float s_ = sA_ * sA * cB + sB_ * cA * sB;                        \
            _Float16 h_, lo_;                                                \
            fsplit(c_, h_, lo_); vch_[j_] = h_; vcl_[j_] = lo_;              \
            fsplit(s_, h_, lo_); vsh_[j_] = h_; vsl_[j_] = lo_;              \
        }                                                                    \
        *(f16x4*)&tCH[BUF][nn][kg * 4] = vch_;                               \
        *(f16x4*)&tCL[BUF][nn][kg * 4] = vcl_;                               \
        *(f16x4*)&tSH[BUF][nn][kg * 4] = vsh_;                               \
        *(f16x4*)&tSL[BUF][nn][kg * 4] = vsl_;                               \
    } while (0)

    __syncthreads();
    INV_TILE(0, 0);
    const int NIT = K_ / 32;   // 16
    // spectral: reduce over K
    for (int it = 0; it < NIT; ++it) {
        __syncthreads();
        int cur = it & 1;
        int off = it * 32 + q * 8;
        f16x8 fch_[2], fcl_[2], fsh_[2], fsl_[2];
        for (int mt = 0; mt < 2; ++mt) {
            fch_[mt] = *(const f16x8*)(fchh + frow[mt] + off);
            fcl_[mt] = *(const f16x8*)(fchl + frow[mt] + off);
            fsh_[mt] = *(const f16x8*)(fshh + frow[mt] + off);
            fsl_[mt] = *(const f16x8*)(fshl + frow[mt] + off);
        }
        f16x8 bch[2], bcl[2], bsh[2], bsl[2];
        for (int nt = 0; nt < 2; ++nt) {
            int r = nt * 16 + l15;
            bch[nt] = *(const f16x8*)&tCH[cur][r][q * 8];
            bcl[nt] = *(const f16x8*)&tCL[cur][r][q * 8];
            bsh[nt] = *(const f16x8*)&tSH[cur][r][q * 8];
            bsl[nt] = *(const f16x8*)&tSL[cur][r][q * 8];
        }
        if (it + 1 < NIT) INV_TILE((it + 1) * 32, cur ^ 1);
        for (int mt = 0; mt < 2; ++mt)
            for (int nt = 0; nt < 2; ++nt) {
                a1[mt][nt] = MFMA16(fch_[mt], bch[nt], a1[mt][nt]);
                a2[mt][nt] = MFMA16(fch_[mt], bcl[nt], a2[mt][nt]);
                a2[mt][nt] = MFMA16(fcl_[mt], bch[nt], a2[mt][nt]);
                a1[mt][nt] = MFMA16(fsh_[mt], bsh[nt], a1[mt][nt]);
                a2[mt][nt] = MFMA16(fsh_[mt], bsl[nt], a2[mt][nt]);
                a2[mt][nt] = MFMA16(fsl_[mt], bsh[nt], a2[mt][nt]);
            }
    }
#undef INV_TILE
    // conv: reduce over C (global operands, unchanged)
    for (int ic = 0; ic < C_; ic += 32) {
        int off = ic + q * 8;
        f16x8 awh[2], awl[2];
        for (int mt = 0; mt < 2; ++mt) {
            awh[mt] = *(const f16x8*)(cwh + crow[mt] + off);
            awl[mt] = *(const f16x8*)(cwl + crow[mt] + off);
        }
        f16x8 bhh[2], bhl[2];
        for (int nt = 0; nt < 2; ++nt) {
            bhh[nt] = *(const f16x8*)(hth + nrow2[nt] + off);
            bhl[nt] = *(const f16x8*)(htl + nrow2[nt] + off);
        }
        for (int mt = 0; mt < 2; ++mt)
            for (int nt = 0; nt < 2; ++nt) {
                a1[mt][nt] = MFMA16(awh[mt], bhh[nt], a1[mt][nt]);
                a2[mt][nt] = MFMA16(awh[mt], bhl[nt], a2[mt][nt]);
                a2[mt][nt] = MFMA16(awl[mt], bhh[nt], a2[mt][nt]);
            }
    }
    for (int mt = 0; mt < 2; ++mt)
        for (int nt = 0; nt < 2; ++nt)
            for (int r = 0; r < 4; ++r) {
                int c = cstrip + mt * 16 + q * 4 + r;
                int n = n0g + nt * 16 + l15;
                float v = a1[mt][nt][r] + a2[mt][nt][r] * INV_SPLIT_SCALE
                        + f0h[b * C_ + c] + conv_b[l * C_ + c];
                if (!last) v = gelu_exact(v);
                hnext[((size_t)b * C_ + c) * N_ + n] = v;
            }
}

// head via MFMA: out[b,n] = fc2_b + sum_j fc2_w[j]*gelu(fc1_b[j] + sum_c w1t[j,c]*h[c,n])
// grid (N/32, B) = 512 blocks; block 128j x 32n; wave 32j x 32n (2x2 tiles)
__global__ __launch_bounds__(256) void head_mfma(const _Float16* __restrict__ hth,
        const _Float16* __restrict__ htl, const _Float16* __restrict__ w1th,
        const _Float16* __restrict__ w1tl, const float* __restrict__ fc1_b,
        const float* __restrict__ fc2_w, const float* __restrict__ fc2_b,
        float* __restrict__ out) {
    __shared__ float red[4][4][2][16];   // [wave][quad][nt][l15]
    int tid = threadIdx.x;
    int w = tid >> 6, lane = tid & 63, l15 = lane & 15, q = lane >> 4;
    int n0 = blockIdx.x * 32, b = blockIdx.y;
    int jstrip = w * 32;
    size_t wrow[2], hrow[2];
    wrow[0] = (size_t)(jstrip + l15) * C_;
    wrow[1] = wrow[0] + (size_t)16 * C_;
    hrow[0] = ((size_t)b * N_ + n0 + l15) * C_;
    hrow[1] = hrow[0] + (size_t)16 * C_;
    f32x4 z = {0.f, 0.f, 0.f, 0.f};
    f32x4 a1[2][2], a2[2][2];
    for (int i = 0; i < 2; ++i)
        for (int j = 0; j < 2; ++j) { a1[i][j] = z; a2[i][j] = z; }
    for (int cc = 0; cc < C_; cc += 32) {
        int off = cc + q * 8;
        f16x8 ah[2], al[2], bh[2], bl[2];
        for (int mt = 0; mt < 2; ++mt) {
            ah[mt] = *(const f16x8*)(w1th + wrow[mt] + off);
            al[mt] = *(const f16x8*)(w1tl + wrow[mt] + off);
        }
        for (int nt = 0; nt < 2; ++nt) {
            bh[nt] = *(const f16x8*)(hth + hrow[nt] + off);
            bl[nt] = *(const f16x8*)(htl + hrow[nt] + off);
        }
        for (int mt = 0; mt < 2; ++mt)
            for (int nt = 0; nt < 2; ++nt) {
                a1[mt][nt] = MFMA16(ah[mt], bh[nt], a1[mt][nt]);
                a2[mt][nt] = MFMA16(ah[mt], bl[nt], a2[mt][nt]);
                a2[mt][nt] = MFMA16(al[mt], bh[nt], a2[mt][nt]);
            }
    }
    float p[2] = {0.f, 0.f};
    for (int mt = 0; mt < 2; ++mt)
        for (int nt = 0; nt < 2; ++nt)
            for (int r = 0; r < 4; ++r) {
                int j = jstrip + mt * 16 + q * 4 + r;
                float v = a1[mt][nt][r] + a2[mt][nt][r] * INV_SPLIT_SCALE + fc1_b[j];
                p[nt] += gelu_exact(v) * fc2_w[j];
            }
    red[w][q][0][l15] = p[0];
    red[w][q][1][l15] = p[1];
    __syncthreads();
    if (tid < 32) {
        int nt = tid >> 4, nl = tid & 15;
        float s = 0.f;
        for (int ww = 0; ww < 4; ++ww)
            for (int qq = 0; qq < 4; ++qq) s += red[ww][qq][nt][nl];
        out[(size_t)b * N_ + n0 + nt * 16 + nl] = s + fc2_b[0];
    }
}

extern "C" void kernel_launch(void* const* d_in, const int* in_sizes, int n_in,
                              void* d_out, int out_size, void* d_ws, size_t ws_size,
                              hipStream_t stream) {
    const float* x      = (const float*)d_in[0];
    const float* xf     = (const float*)d_in[1];
    const int*   ind    = (const int*)d_in[2];
    const float* modes  = (const float*)d_in[3];
    const float* fc0_w  = (const float*)d_in[4];
    const float* fc0_b  = (const float*)d_in[5];
    const float* wc     = (const float*)d_in[6];
    const float* ws     = (const float*)d_in[7];
    const float* w0     = (const float*)d_in[8];
    const float* conv_w = (const float*)d_in[9];
    const float* conv_b = (const float*)d_in[10];
    const float* fc1_w  = (const float*)d_in[11];
    const float* fc1_b  = (const float*)d_in[12];
    const float* fc2_w  = (const float*)d_in[13];
    const float* fc2_b  = (const float*)d_in[14];
    float* out = (float*)d_out;

    float* wsf = (float*)d_ws;
    float* h   = wsf + H_OFF;
    float* h2  = wsf + H2_OFF;
    _Float16* hah = (_Float16*)(wsf + HAH_OFF);
    _Float16* hal = (_Float16*)(wsf + HAL_OFF);
    _Float16* hth = (_Float16*)(wsf + HTH_OFF);
    _Float16* htl = (_Float16*)(wsf + HTL_OFF);
    float* wqn = wsf + WQN_OFF;
    float* gxy = wsf + GXY_OFF;
    float* xch = wsf + XCH_OFF;
    float* xsh = wsf + XSH_OFF;
    _Float16* fchh = (_Float16*)(wsf + FCHH_OFF);
    _Float16* fchl = (_Float16*)(wsf + FCHL_OFF);
    _Float16* fshh = (_Float16*)(wsf + FSHH_OFF);
    _Float16* fshl = (_Float16*)(wsf + FSHL_OFF);
    _Float16* cwh = (_Float16*)(wsf + CWH_OFF);
    _Float16* cwl = (_Float16*)(wsf + CWL_OFF);
    float* x0h = wsf + X0_OFF;
    float* f0h = wsf + F0_OFF;
    float* xcp = wsf + XCP_OFF;
    float* xsp = wsf + XSP_OFF;
    _Float16* w1th = (_Float16*)(wsf + W1TH_OFF);
    _Float16* w1tl = (_Float16*)(wsf + W1TL_OFF);
    float* tab = wsf + TAB_OFF;

    prep_kernel<<<dim3(N_ / 256, C_, B_), 256, 0, stream>>>(x, xf, ind, fc0_w, fc0_b,
                                                            h, wqn, gxy);
    tab_kernel<<<dim3(N_ / 256, B_), 256, 0, stream>>>(gxy, tab);
    conv_split<<<dim3(L_ * C_ * C_ / 256), 256, 0, stream>>>(conv_w, cwh, cwl);
    w1_split<<<dim3(C_ * FCD_ / 256), 256, 0, stream>>>(fc1_w, w1th, w1tl);

    float* cur = h;
    float* nxt = h2;
    for (int l = 0; l < L_; ++l) {
        split_h<<<dim3(N_ / 64, C_ / 64, B_), 256, 0, stream>>>(cur, wqn, hah, hal, hth, htl);
        fwd_mfma<<<dim3(K_ / 32, SPLIT_, B_), 256, 0, stream>>>(hah, hal, tab, modes,
                                                                xcp, xsp);
        red_kernel<<<dim3(B_ * C_ * K_ / 256), 256, 0, stream>>>(xcp, xsp, xch, xsh);
        x0_kernel<<<dim3(C_, B_), 256, 0, stream>>>(cur, wqn, x0h);
        f0_kernel<<<dim3(B_), C_, 0, stream>>>(x0h, w0, l, f0h);
        mix_kernel<<<dim3(K_ / 64, C_), 256, 0, stream>>>(xch, xsh, wc, ws, l,
                                                          fchh, fchl, fshh, fshl);
        inv_mfma<<<dim3(N_ / 32, B_), 256, 0, stream>>>(fchh, fchl, fshh, fshl,
            tab, modes, cwh, cwl, hth, htl, f0h, conv_b, l,
            (l == L_ - 1) ? 1 : 0, nxt);
        float* t = cur; cur = nxt; nxt = t;
    }
    split_h<<<dim3(N_ / 64, C_ / 64, B_), 256, 0, stream>>>(cur, wqn, hah, hal, hth, htl);
    head_mfma<<<dim3(N_ / 32, B_), 256, 0, stream>>>(hth, htl, w1th, w1tl,
                                                     fc1_b, fc2_w, fc2_b, out);
}

// Round 6
// 750.290 us; speedup vs baseline: 1.1471x; 1.1471x over previous
//
#include <hip/hip_runtime.h>
#include <cmath>

#define B_ 4
#define N_ 4096
#define NF_ 8192
#define K_ 512
#define C_ 128
#define L_ 4
#define FCD_ 128
#define SPLIT_ 8

typedef _Float16 f16x8 __attribute__((ext_vector_type(8)));
typedef _Float16 f16x4 __attribute__((ext_vector_type(4)));
typedef float f32x4 __attribute__((ext_vector_type(4)));

#define MFMA16(a, b, c) __builtin_amdgcn_mfma_f32_16x16x32_f16((a), (b), (c), 0, 0, 0)

static const float SPLIT_SCALE = 2048.0f;      // 2^11
static const float INV_SPLIT_SCALE = 1.0f / 2048.0f;

// ---- workspace layout (float offsets; f16 arrays use count/2 floats) ----
static const size_t SZ_H   = (size_t)B_ * C_ * N_;       // fp32
static const size_t SZ_HS  = (size_t)B_ * C_ * N_ / 2;   // f16 split
static const size_t SZ_FS  = (size_t)B_ * C_ * K_ / 2;   // f16 split of fch/fsh
static const size_t SZ_CW  = (size_t)L_ * C_ * C_ / 2;   // f16 split conv_w
static const size_t SZ_W1  = (size_t)C_ * FCD_ / 2;      // f16 split fc1_w^T

static const size_t H_OFF    = 0;
static const size_t H2_OFF   = H_OFF + SZ_H;
static const size_t HAH_OFF  = H2_OFF + SZ_H;
static const size_t HAL_OFF  = HAH_OFF + SZ_HS;
static const size_t HTH_OFF  = HAL_OFF + SZ_HS;
static const size_t HTL_OFF  = HTH_OFF + SZ_HS;
static const size_t WQN_OFF  = HTL_OFF + SZ_HS;                  // B*N fp32
static const size_t GXY_OFF  = WQN_OFF + (size_t)B_ * N_;        // B*N*2 fp32 (gx,gy)
static const size_t XCH_OFF  = GXY_OFF + (size_t)B_ * N_ * 2;    // B*C*K fp32
static const size_t XSH_OFF  = XCH_OFF + (size_t)B_ * C_ * K_;
static const size_t FCHH_OFF = XSH_OFF + (size_t)B_ * C_ * K_;
static const size_t FCHL_OFF = FCHH_OFF + SZ_FS;
static const size_t FSHH_OFF = FCHL_OFF + SZ_FS;
static const size_t FSHL_OFF = FSHH_OFF + SZ_FS;
static const size_t CWH_OFF  = FSHL_OFF + SZ_FS;
static const size_t CWL_OFF  = CWH_OFF + SZ_CW;
static const size_t X0_OFF   = CWL_OFF + SZ_CW;                  // B*C
static const size_t F0_OFF   = X0_OFF + (size_t)B_ * C_;
static const size_t XCP_OFF  = F0_OFF + (size_t)B_ * C_;         // SPLIT*B*C*K
static const size_t XSP_OFF  = XCP_OFF + (size_t)SPLIT_ * B_ * C_ * K_;
static const size_t W1TH_OFF = XSP_OFF + (size_t)SPLIT_ * B_ * C_ * K_;
static const size_t W1TL_OFF = W1TH_OFF + SZ_W1;
// end ~= 13.9M floats ~= 56 MB

__device__ __forceinline__ float gelu_exact(float v) {
    return v * 0.5f * (1.0f + erff(v * 0.70710678118654752440f));
}

__device__ __forceinline__ void fsplit(float v, _Float16& hi, _Float16& lo) {
    hi = (_Float16)v;
    lo = (_Float16)((v - (float)hi) * SPLIT_SCALE);
}

// h[b,c,n] = fc0(x);  wqn[b,n] = wq[b,ind[n]] * N;  gxy[b,n] = grid[b,ind[n],0:2]
__global__ void prep_kernel(const float* __restrict__ x, const float* __restrict__ xf,
                            const int* __restrict__ ind, const float* __restrict__ fc0_w,
                            const float* __restrict__ fc0_b, float* __restrict__ h,
                            float* __restrict__ wqn, float* __restrict__ gxy) {
    int n = blockIdx.x * 256 + threadIdx.x;
    int c = blockIdx.y;
    int b = blockIdx.z;
    const float* xp = x + ((size_t)b * N_ + n) * 3;
    float acc = fc0_b[c] + xp[0] * fc0_w[0 * C_ + c] + xp[1] * fc0_w[1 * C_ + c]
              + xp[2] * fc0_w[2 * C_ + c];
    h[((size_t)b * C_ + c) * N_ + n] = acc;
    if (c == 0) {
        int g = ind[n];
        const float* xfp = xf + ((size_t)b * NF_ + g) * 4;
        wqn[b * N_ + n] = xfp[2] * (float)N_;
        gxy[((size_t)b * N_ + n) * 2 + 0] = xfp[0];
        gxy[((size_t)b * N_ + n) * 2 + 1] = xfp[1];
    }
}

// conv_w and fc1_w^T -> f16 hi/lo, one dispatch (range split)
__global__ void weights_split(const float* __restrict__ conv_w,
                              const float* __restrict__ fc1_w,
                              _Float16* __restrict__ cwh, _Float16* __restrict__ cwl,
                              _Float16* __restrict__ w1th, _Float16* __restrict__ w1tl) {
    int t = blockIdx.x * 256 + threadIdx.x;
    const int NCW = L_ * C_ * C_;
    _Float16 hi, lo;
    if (t < NCW) {
        fsplit(conv_w[t], hi, lo);
        cwh[t] = hi; cwl[t] = lo;
    } else {
        int u = t - NCW;               // u = j*C_ + c
        int j = u >> 7, c = u & (C_ - 1);
        fsplit(fc1_w[c * FCD_ + j], hi, lo);
        w1th[u] = hi; w1tl[u] = lo;
    }
}

__device__ __forceinline__ unsigned int pack2(_Float16 a, _Float16 b) {
    union { _Float16 f[2]; unsigned int u; } x;
    x.f[0] = a; x.f[1] = b;
    return x.u;
}

__device__ __forceinline__ void unpack2(unsigned int v, _Float16& a, _Float16& b) {
    union { _Float16 f[2]; unsigned int u; } x;
    x.u = v;
    a = x.f[0]; b = x.f[1];
}

// layer-0 only: hA = split(h*wqn) [c][n];  hT = split(h) [n][c]
__global__ __launch_bounds__(256) void split_h(const float* __restrict__ h,
        const float* __restrict__ wqn, _Float16* __restrict__ hah,
        _Float16* __restrict__ hal, _Float16* __restrict__ hth,
        _Float16* __restrict__ htl) {
    __shared__ unsigned int pk[64][65];
    int tid = threadIdx.x;
    int n0 = blockIdx.x * 64, c0 = blockIdx.y * 64, b = blockIdx.z;
    int col = tid & 63, row4 = tid >> 6;
    for (int r = row4; r < 64; r += 4) {
        int c = c0 + r, n = n0 + col;
        float v = h[((size_t)b * C_ + c) * N_ + n];
        _Float16 ph, pl;
        fsplit(v, ph, pl);
        pk[r][col] = pack2(ph, pl);
        float a = v * wqn[b * N_ + n];
        _Float16 ah, al;
        fsplit(a, ah, al);
        size_t o = ((size_t)b * C_ + c) * N_ + n;
        hah[o] = ah; hal[o] = al;
    }
    __syncthreads();
    for (int r = row4; r < 64; r += 4) {
        int n = n0 + r, c = c0 + col;
        _Float16 ph, pl;
        unpack2(pk[col][r], ph, pl);
        size_t o = ((size_t)b * N_ + n) * C_ + c;
        hth[o] = ph; htl[o] = pl;
    }
}

// fwd MFMA with on-the-fly LDS bases (sincos):
// xcp[p,b,c,k] = sum_{n in chunk p} (h*wqn)*cos ; xsp = -sum (h*wqn)*sin
// grid (K/32, SPLIT, B) = 512 blocks; block: 128c x 32k; wave: 32c x 32k (2x2 tiles)
__global__ __launch_bounds__(256) void fwd_mfma(const _Float16* __restrict__ hah,
        const _Float16* __restrict__ hal, const float* __restrict__ gxy,
        const float* __restrict__ modes, float* __restrict__ xcp,
        float* __restrict__ xsp) {
    __shared__ __align__(16) _Float16 tCH[2][32][40];
    __shared__ __align__(16) _Float16 tCL[2][32][40];
    __shared__ __align__(16) _Float16 tSH[2][32][40];
    __shared__ __align__(16) _Float16 tSL[2][32][40];
    __shared__ float gx_s[N_ / SPLIT_], gy_s[N_ / SPLIT_];
    int tid = threadIdx.x;
    int w = tid >> 6, lane = tid & 63, l15 = lane & 15, q = lane >> 4;
    int k0g = blockIdx.x * 32, p = blockIdx.y, b = blockIdx.z;
    int cstrip = w * 32;
    // preload grid slice for this p-chunk (512 n's)
    {
        const float* g = gxy + ((size_t)b * N_ + p * (N_ / SPLIT_)) * 2;
        float4 v = *(const float4*)(g + tid * 4);
        gx_s[tid * 2 + 0] = v.x; gy_s[tid * 2 + 0] = v.y;
        gx_s[tid * 2 + 1] = v.z; gy_s[tid * 2 + 1] = v.w;
    }
    // per-thread fixed k for tile compute
    int kk = tid & 31, ng = tid >> 5;   // ng in 0..7, covers nn = ng*4+j
    float mx = modes[(k0g + kk) * 2 + 0];
    float my = modes[(k0g + kk) * 2 + 1];

    size_t arow[2];
    arow[0] = ((size_t)b * C_ + cstrip + l15) * N_;
    arow[1] = arow[0] + (size_t)16 * N_;
    f32x4 z = {0.f, 0.f, 0.f, 0.f};
    f32x4 aC1[2][2], aC2[2][2], aS1[2][2], aS2[2][2];
    for (int i = 0; i < 2; ++i)
        for (int j = 0; j < 2; ++j) {
            aC1[i][j] = z; aC2[i][j] = z; aS1[i][j] = z; aS2[i][j] = z;
        }

#define FWD_TILE(ITER, BUF) do {                                             \
        int nb_ = (ITER) * 32;                                               \
        f16x4 vch_, vcl_, vsh_, vsl_;                                        \
        for (int j_ = 0; j_ < 4; ++j_) {                                     \
            int nn_ = ng * 4 + j_;                                           \
            float t_ = gx_s[nb_ + nn_] * mx + gy_s[nb_ + nn_] * my;          \
            float s_, c_;                                                    \
            sincosf(t_, &s_, &c_);                                           \
            _Float16 h_, lo_;                                                \
            fsplit(c_, h_, lo_); vch_[j_] = h_; vcl_[j_] = lo_;              \
            fsplit(s_, h_, lo_); vsh_[j_] = h_; vsl_[j_] = lo_;              \
        }                                                                    \
        *(f16x4*)&tCH[BUF][kk][ng * 4] = vch_;                               \
        *(f16x4*)&tCL[BUF][kk][ng * 4] = vcl_;                               \
        *(f16x4*)&tSH[BUF][kk][ng * 4] = vsh_;                               \
        *(f16x4*)&tSL[BUF][kk][ng * 4] = vsl_;                               \
    } while (0)

    __syncthreads();
    FWD_TILE(0, 0);
    const int NIT = (N_ / SPLIT_) / 32;   // 16
    for (int it = 0; it < NIT; ++it) {
        __syncthreads();
        int cur = it & 1;
        int off = p * (N_ / SPLIT_) + it * 32 + q * 8;
        f16x8 ah[2], al[2];
        for (int mt = 0; mt < 2; ++mt) {
            ah[mt] = *(const f16x8*)(hah + arow[mt] + off);
            al[mt] = *(const f16x8*)(hal + arow[mt] + off);
        }
        f16x8 bch[2], bcl[2], bsh[2], bsl[2];
        for (int kt = 0; kt < 2; ++kt) {
            int r = kt * 16 + l15;
            bch[kt] = *(const f16x8*)&tCH[cur][r][q * 8];
            bcl[kt] = *(const f16x8*)&tCL[cur][r][q * 8];
            bsh[kt] = *(const f16x8*)&tSH[cur][r][q * 8];
            bsl[kt] = *(const f16x8*)&tSL[cur][r][q * 8];
        }
        if (it + 1 < NIT) FWD_TILE(it + 1, cur ^ 1);
        for (int mt = 0; mt < 2; ++mt)
            for (int kt = 0; kt < 2; ++kt) {
                aC1[mt][kt] = MFMA16(ah[mt], bch[kt], aC1[mt][kt]);
                aC2[mt][kt] = MFMA16(ah[mt], bcl[kt], aC2[mt][kt]);
                aC2[mt][kt] = MFMA16(al[mt], bch[kt], aC2[mt][kt]);
                aS1[mt][kt] = MFMA16(ah[mt], bsh[kt], aS1[mt][kt]);
                aS2[mt][kt] = MFMA16(ah[mt], bsl[kt], aS2[mt][kt]);
                aS2[mt][kt] = MFMA16(al[mt], bsh[kt], aS2[mt][kt]);
            }
    }
#undef FWD_TILE
    size_t pb = (size_t)p * B_ + b;
    for (int mt = 0; mt < 2; ++mt)
        for (int kt = 0; kt < 2; ++kt)
            for (int r = 0; r < 4; ++r) {
                int c = cstrip + mt * 16 + q * 4 + r;
                int k = k0g + kt * 16 + l15;
                size_t o = (pb * C_ + c) * K_ + k;
                xcp[o] = aC1[mt][kt][r] + aC2[mt][kt][r] * INV_SPLIT_SCALE;
                xsp[o] = -(aS1[mt][kt][r] + aS2[mt][kt][r] * INV_SPLIT_SCALE);
            }
}

__global__ void red_kernel(const float* __restrict__ xcp, const float* __restrict__ xsp,
                           float* __restrict__ xch, float* __restrict__ xsh) {
    int t = blockIdx.x * 256 + threadIdx.x;
    const int BCK = B_ * C_ * K_;
    float a = 0.f, s = 0.f;
    for (int p = 0; p < SPLIT_; ++p) {
        a += xcp[(size_t)p * BCK + t];
        s += xsp[(size_t)p * BCK + t];
    }
    xch[t] = a; xsh[t] = s;
}

// x0h[b,c] = sum_n h*wqn
__global__ void x0_kernel(const float* __restrict__ h, const float* __restrict__ wqn,
                          float* __restrict__ x0h) {
    int c = blockIdx.x, b = blockIdx.y;
    int tid = threadIdx.x;
    const float* hp = h + ((size_t)b * C_ + c) * N_;
    const float* wq = wqn + b * N_;
    float a = 0.f;
    for (int n = tid; n < N_; n += 256) a += hp[n] * wq[n];
    __shared__ float red[4];
    for (int off = 32; off; off >>= 1) a += __shfl_down(a, off, 64);
    if ((tid & 63) == 0) red[tid >> 6] = a;
    __syncthreads();
    if (tid == 0) x0h[b * C_ + c] = red[0] + red[1] + red[2] + red[3];
}

// f0h[b,o] = (sum_i x0h[b,i]*w0[l,i,o]) / NF
__global__ void f0_kernel(const float* __restrict__ x0h, const float* __restrict__ w0,
                          int l, float* __restrict__ f0h) {
    int o = threadIdx.x, b = blockIdx.x;
    const float* w = w0 + (size_t)l * C_ * C_;
    float a = 0.f;
    for (int i = 0; i < C_; ++i) a += x0h[b * C_ + i] * w[i * C_ + o];
    f0h[b * C_ + o] = a * (1.0f / NF_);
}

// fch' = (2/NF)*sum_i(xch*wc - xsh*ws); fsh' = (2/NF)*sum_i(xsh*wc + xch*ws)
// writes f16 splits directly; fsh split is NEGATED (inv only accumulates +)
__global__ __launch_bounds__(256) void mix_kernel(const float* __restrict__ xch,
        const float* __restrict__ xsh, const float* __restrict__ wc,
        const float* __restrict__ ws, int l, _Float16* __restrict__ fchh,
        _Float16* __restrict__ fchl, _Float16* __restrict__ fshh,
        _Float16* __restrict__ fshl) {
    __shared__ float red[512 * 5];
    int tid = threadIdx.x;
    int lane = tid & 63;
    int g = tid >> 6;
    int k = blockIdx.x * 64 + lane;
    int o = blockIdx.y;
    const float* wcb = wc + ((size_t)l * C_ * C_ + o) * K_ + k;
    const float* wsb = ws + ((size_t)l * C_ * C_ + o) * K_ + k;
    float fc[4] = {0, 0, 0, 0}, fs[4] = {0, 0, 0, 0};
    int i0 = g * 32;
#pragma unroll 4
    for (int ii = 0; ii < 32; ++ii) {
        int i = i0 + ii;
        float wci = wcb[(size_t)i * (C_ * K_)];
        float wsi = wsb[(size_t)i * (C_ * K_)];
#pragma unroll
        for (int b = 0; b < 4; ++b) {
            float xc = xch[((size_t)b * C_ + i) * K_ + k];
            float xs = xsh[((size_t)b * C_ + i) * K_ + k];
            fc[b] += xc * wci - xs * wsi;
            fs[b] += xs * wci + xc * wsi;
        }
    }
#pragma unroll
    for (int b = 0; b < 4; ++b) {
        red[((b * 2 + 0) * 64 + lane) * 5 + g] = fc[b];
        red[((b * 2 + 1) * 64 + lane) * 5 + g] = fs[b];
    }
    __syncthreads();
    const float sc = 2.0f / NF_;
    for (int v = tid; v < 512; v += 256) {
        float sum = (red[v * 5 + 0] + red[v * 5 + 1] + red[v * 5 + 2] + red[v * 5 + 3]) * sc;
        int lane2 = v & 63;
        int bs = v >> 6;
        int b = bs >> 1, s = bs & 1;
        size_t idx = ((size_t)b * C_ + o) * K_ + blockIdx.x * 64 + lane2;
        _Float16 hi, lo;
        if (s == 0) {
            fsplit(sum, hi, lo);
            fchh[idx] = hi; fchl[idx] = lo;
        } else {
            fsplit(-sum, hi, lo);
            fshh[idx] = hi; fshl[idx] = lo;
        }
    }
}

// inv MFMA with on-the-fly LDS bases + FUSED split_h epilogue:
// v[b,c,n] = gelu?( sum_k fch*cos + fshN*sin + sum_i cw[c,i]*h[i,n] + f0h + conv_b )
// writes: hth/htl = split(v) [n][c] always; and for !last:
//         hnext fp32 (for next x0), hah/hal = split(v*wqn) [c][n]
// NOTE: hth/htl alias oth/otl (in-place update). Conv reads are block-local in n
// (rows n0g..n0g+31 only), so a single __syncthreads() before the epilogue
// makes the in-place update safe. No __restrict__ on the aliasing params.
// grid (N/32, B) = 512 blocks; block 128c x 32n; wave 32c x 32n (2x2 tiles)
__global__ __launch_bounds__(256) void inv_mfma(const _Float16* __restrict__ fchh,
        const _Float16* __restrict__ fchl, const _Float16* __restrict__ fshh,
        const _Float16* __restrict__ fshl, const float* __restrict__ gxy,
        const float* __restrict__ modes, const _Float16* __restrict__ cwh,
        const _Float16* __restrict__ cwl, const _Float16* hth,
        const _Float16* htl, const float* __restrict__ f0h,
        const float* __restrict__ conv_b, const float* __restrict__ wqn,
        int l, int last, float* __restrict__ hnext,
        _Float16* __restrict__ oah, _Float16* __restrict__ oal,
        _Float16* oth, _Float16* otl) {
    __shared__ __align__(16) _Float16 tCH[2][32][40];
    __shared__ __align__(16) _Float16 tCL[2][32][40];
    __shared__ __align__(16) _Float16 tSH[2][32][40];
    __shared__ __align__(16) _Float16 tSL[2][32][40];
    __shared__ float mx_s[K_], my_s[K_];
    int tid = threadIdx.x;
    int w = tid >> 6, lane = tid & 63, l15 = lane & 15, q = lane >> 4;
    int n0g = blockIdx.x * 32, b = blockIdx.y;
    int cstrip = w * 32;
    // preload all modes (K*2 floats)
    {
        float4 v = *(const float4*)(modes + tid * 4);
        mx_s[tid * 2 + 0] = v.x; my_s[tid * 2 + 0] = v.y;
        mx_s[tid * 2 + 1] = v.z; my_s[tid * 2 + 1] = v.w;
    }
    // per-thread fixed n for tile compute
    int nn = tid & 31, kg = tid >> 5;   // kg in 0..7, covers kk = kg*4+j
    float gx = gxy[((size_t)b * N_ + n0g + nn) * 2 + 0];
    float gy = gxy[((size_t)b * N_ + n0g + nn) * 2 + 1];

    size_t frow[2], nrow2[2], crow[2];
    frow[0] = ((size_t)b * C_ + cstrip + l15) * K_;
    frow[1] = frow[0] + (size_t)16 * K_;
    nrow2[0] = ((size_t)b * N_ + n0g + l15) * C_;
    nrow2[1] = nrow2[0] + (size_t)16 * C_;
    crow[0] = ((size_t)l * C_ + cstrip + l15) * C_;
    crow[1] = crow[0] + (size_t)16 * C_;
    f32x4 z = {0.f, 0.f, 0.f, 0.f};
    f32x4 a1[2][2], a2[2][2];
    for (int i = 0; i < 2; ++i)
        for (int j = 0; j < 2; ++j) { a1[i][j] = z; a2[i][j] = z; }

#define INV_TILE(KC, BUF) do {                                               \
        f16x4 vch_, vcl_, vsh_, vsl_;                                        \
        for (int j_ = 0; j_ < 4; ++j_) {                                     \
            int kk_ = (KC) + kg * 4 + j_;                                    \
            float t_ = gx * mx_s[kk_] + gy * my_s[kk_];                      \
            float s_, c_;                                                    \
            sincosf(t_, &s_, &c_);                                           \
            _Float16 h_, lo_;                                                \
            fsplit(c_, h_, lo_); vch_[j_] = h_; vcl_[j_] = lo_;              \
            fsplit(s_, h_, lo_); vsh_[j_] = h_; vsl_[j_] = lo_;              \
        }                                                                    \
        *(f16x4*)&tCH[BUF][nn][kg * 4] = vch_;                               \
        *(f16x4*)&tCL[BUF][nn][kg * 4] = vcl_;                               \
        *(f16x4*)&tSH[BUF][nn][kg * 4] = vsh_;                               \
        *(f16x4*)&tSL[BUF][nn][kg * 4] = vsl_;                               \
    } while (0)

    __syncthreads();
    INV_TILE(0, 0);
    const int NIT = K_ / 32;   // 16
    // spectral: reduce over K
    for (int it = 0; it < NIT; ++it) {
        __syncthreads();
        int cur = it & 1;
        int off = it * 32 + q * 8;
        f16x8 fch_[2], fcl_[2], fsh_[2], fsl_[2];
        for (int mt = 0; mt < 2; ++mt) {
            fch_[mt] = *(const f16x8*)(fchh + frow[mt] + off);
            fcl_[mt] = *(const f16x8*)(fchl + frow[mt] + off);
            fsh_[mt] = *(const f16x8*)(fshh + frow[mt] + off);
            fsl_[mt] = *(const f16x8*)(fshl + frow[mt] + off);
        }
        f16x8 bch[2], bcl[2], bsh[2], bsl[2];
        for (int nt = 0; nt < 2; ++nt) {
            int r = nt * 16 + l15;
            bch[nt] = *(const f16x8*)&tCH[cur][r][q * 8];
            bcl[nt] = *(const f16x8*)&tCL[cur][r][q * 8];
            bsh[nt] = *(const f16x8*)&tSH[cur][r][q * 8];
            bsl[nt] = *(const f16x8*)&tSL[cur][r][q * 8];
        }
        if (it + 1 < NIT) INV_TILE((it + 1) * 32, cur ^ 1);
        for (int mt = 0; mt < 2; ++mt)
            for (int nt = 0; nt < 2; ++nt) {
                a1[mt][nt] = MFMA16(fch_[mt], bch[nt], a1[mt][nt]);
                a2[mt][nt] = MFMA16(fch_[mt], bcl[nt], a2[mt][nt]);
                a2[mt][nt] = MFMA16(fcl_[mt], bch[nt], a2[mt][nt]);
                a1[mt][nt] = MFMA16(fsh_[mt], bsh[nt], a1[mt][nt]);
                a2[mt][nt] = MFMA16(fsh_[mt], bsl[nt], a2[mt][nt]);
                a2[mt][nt] = MFMA16(fsl_[mt], bsh[nt], a2[mt][nt]);
            }
    }
#undef INV_TILE
    // conv: reduce over C (reads hth/htl rows n0g..n0g+31 only)
    for (int ic = 0; ic < C_; ic += 32) {
        int off = ic + q * 8;
        f16x8 awh[2], awl[2];
        for (int mt = 0; mt < 2; ++mt) {
            awh[mt] = *(const f16x8*)(cwh + crow[mt] + off);
            awl[mt] = *(const f16x8*)(cwl + crow[mt] + off);
        }
        f16x8 bhh[2], bhl[2];
        for (int nt = 0; nt < 2; ++nt) {
            bhh[nt] = *(const f16x8*)(hth + nrow2[nt] + off);
            bhl[nt] = *(const f16x8*)(htl + nrow2[nt] + off);
        }
        for (int mt = 0; mt < 2; ++mt)
            for (int nt = 0; nt < 2; ++nt) {
                a1[mt][nt] = MFMA16(awh[mt], bhh[nt], a1[mt][nt]);
                a2[mt][nt] = MFMA16(awh[mt], bhl[nt], a2[mt][nt]);
                a2[mt][nt] = MFMA16(awl[mt], bhh[nt], a2[mt][nt]);
            }
    }
    // ALL waves must finish reading old hth/htl before any epilogue store
    __syncthreads();
    // fused epilogue: emit v, split(v), split(v*wqn)
    float wq2[2];
    wq2[0] = wqn[b * N_ + n0g + l15];
    wq2[1] = wqn[b * N_ + n0g + 16 + l15];
    for (int mt = 0; mt < 2; ++mt)
        for (int nt = 0; nt < 2; ++nt)
            for (int r = 0; r < 4; ++r) {
                int c = cstrip + mt * 16 + q * 4 + r;
                int n = n0g + nt * 16 + l15;
                float v = a1[mt][nt][r] + a2[mt][nt][r] * INV_SPLIT_SCALE
                        + f0h[b * C_ + c] + conv_b[l * C_ + c];
                if (!last) v = gelu_exact(v);
                size_t onc = ((size_t)b * N_ + n) * C_ + c;
                _Float16 ph, pl;
                fsplit(v, ph, pl);
                oth[onc] = ph; otl[onc] = pl;
                if (!last) {
                    size_t ocn = ((size_t)b * C_ + c) * N_ + n;
                    hnext[ocn] = v;
                    float a = v * wq2[nt];
                    _Float16 ah, al;
                    fsplit(a, ah, al);
                    oah[ocn] = ah; oal[ocn] = al;
                }
            }
}

// head via MFMA: out[b,n] = fc2_b + sum_j fc2_w[j]*gelu(fc1_b[j] + sum_c w1t[j,c]*h[c,n])
// grid (N/32, B) = 512 blocks; block 128j x 32n; wave 32j x 32n (2x2 tiles)
__global__ __launch_bounds__(256) void head_mfma(const _Float16* __restrict__ hth,
        const _Float16* __restrict__ htl, const _Float16* __restrict__ w1th,
        const _Float16* __restrict__ w1tl, const float* __restrict__ fc1_b,
        const float* __restrict__ fc2_w, const float* __restrict__ fc2_b,
        float* __restrict__ out) {
    __shared__ float red[4][4][2][16];   // [wave][quad][nt][l15]
    int tid = threadIdx.x;
    int w = tid >> 6, lane = tid & 63, l15 = lane & 15, q = lane >> 4;
    int n0 = blockIdx.x * 32, b = blockIdx.y;
    int jstrip = w * 32;
    size_t wrow[2], hrow[2];
    wrow[0] = (size_t)(jstrip + l15) * C_;
    wrow[1] = wrow[0] + (size_t)16 * C_;
    hrow[0] = ((size_t)b * N_ + n0 + l15) * C_;
    hrow[1] = hrow[0] + (size_t)16 * C_;
    f32x4 z = {0.f, 0.f, 0.f, 0.f};
    f32x4 a1[2][2], a2[2][2];
    for (int i = 0; i < 2; ++i)
        for (int j = 0; j < 2; ++j) { a1[i][j] = z; a2[i][j] = z; }
    for (int cc = 0; cc < C_; cc += 32) {
        int off = cc + q * 8;
        f16x8 ah[2], al[2], bh[2], bl[2];
        for (int mt = 0; mt < 2; ++mt) {
            ah[mt] = *(const f16x8*)(w1th + wrow[mt] + off);
            al[mt] = *(const f16x8*)(w1tl + wrow[mt] + off);
        }
        for (int nt = 0; nt < 2; ++nt) {
            bh[nt] = *(const f16x8*)(hth + hrow[nt] + off);
            bl[nt] = *(const f16x8*)(htl + hrow[nt] + off);
        }
        for (int mt = 0; mt < 2; ++mt)
            for (int nt = 0; nt < 2; ++nt) {
                a1[mt][nt] = MFMA16(ah[mt], bh[nt], a1[mt][nt]);
                a2[mt][nt] = MFMA16(ah[mt], bl[nt], a2[mt][nt]);
                a2[mt][nt] = MFMA16(al[mt], bh[nt], a2[mt][nt]);
            }
    }
    float p[2] = {0.f, 0.f};
    for (int mt = 0; mt < 2; ++mt)
        for (int nt = 0; nt < 2; ++nt)
            for (int r = 0; r < 4; ++r) {
                int j = jstrip + mt * 16 + q * 4 + r;
                float v = a1[mt][nt][r] + a2[mt][nt][r] * INV_SPLIT_SCALE + fc1_b[j];
                p[nt] += gelu_exact(v) * fc2_w[j];
            }
    red[w][q][0][l15] = p[0];
    red[w][q][1][l15] = p[1];
    __syncthreads();
    if (tid < 32) {
        int nt = tid >> 4, nl = tid & 15;
        float s = 0.f;
        for (int ww = 0; ww < 4; ++ww)
            for (int qq = 0; qq < 4; ++qq) s += red[ww][qq][nt][nl];
        out[(size_t)b * N_ + n0 + nt * 16 + nl] = s + fc2_b[0];
    }
}

extern "C" void kernel_launch(void* const* d_in, const int* in_sizes, int n_in,
                              void* d_out, int out_size, void* d_ws, size_t ws_size,
                              hipStream_t stream) {
    const float* x      = (const float*)d_in[0];
    const float* xf     = (const float*)d_in[1];
    const int*   ind    = (const int*)d_in[2];
    const float* modes  = (const float*)d_in[3];
    const float* fc0_w  = (const float*)d_in[4];
    const float* fc0_b  = (const float*)d_in[5];
    const float* wc     = (const float*)d_in[6];
    const float* ws     = (const float*)d_in[7];
    const float* w0     = (const float*)d_in[8];
    const float* conv_w = (const float*)d_in[9];
    const float* conv_b = (const float*)d_in[10];
    const float* fc1_w  = (const float*)d_in[11];
    const float* fc1_b  = (const float*)d_in[12];
    const float* fc2_w  = (const float*)d_in[13];
    const float* fc2_b  = (const float*)d_in[14];
    float* out = (float*)d_out;

    float* wsf = (float*)d_ws;
    float* h   = wsf + H_OFF;
    float* h2  = wsf + H2_OFF;
    _Float16* hah = (_Float16*)(wsf + HAH_OFF);
    _Float16* hal = (_Float16*)(wsf + HAL_OFF);
    _Float16* hth = (_Float16*)(wsf + HTH_OFF);
    _Float16* htl = (_Float16*)(wsf + HTL_OFF);
    float* wqn = wsf + WQN_OFF;
    float* gxy = wsf + GXY_OFF;
    float* xch = wsf + XCH_OFF;
    float* xsh = wsf + XSH_OFF;
    _Float16* fchh = (_Float16*)(wsf + FCHH_OFF);
    _Float16* fchl = (_Float16*)(wsf + FCHL_OFF);
    _Float16* fshh = (_Float16*)(wsf + FSHH_OFF);
    _Float16* fshl = (_Float16*)(wsf + FSHL_OFF);
    _Float16* cwh = (_Float16*)(wsf + CWH_OFF);
    _Float16* cwl = (_Float16*)(wsf + CWL_OFF);
    float* x0h = wsf + X0_OFF;
    float* f0h = wsf + F0_OFF;
    float* xcp = wsf + XCP_OFF;
    float* xsp = wsf + XSP_OFF;
    _Float16* w1th = (_Float16*)(wsf + W1TH_OFF);
    _Float16* w1tl = (_Float16*)(wsf + W1TL_OFF);

    prep_kernel<<<dim3(N_ / 256, C_, B_), 256, 0, stream>>>(x, xf, ind, fc0_w, fc0_b,
                                                            h, wqn, gxy);
    weights_split<<<dim3((L_ * C_ * C_ + C_ * FCD_) / 256), 256, 0, stream>>>(
        conv_w, fc1_w, cwh, cwl, w1th, w1tl);
    split_h<<<dim3(N_ / 64, C_ / 64, B_), 256, 0, stream>>>(h, wqn, hah, hal, hth, htl);

    float* cur = h;
    float* nxt = h2;
    for (int l = 0; l < L_; ++l) {
        fwd_mfma<<<dim3(K_ / 32, SPLIT_, B_), 256, 0, stream>>>(hah, hal, gxy, modes,
                                                                xcp, xsp);
        red_kernel<<<dim3(B_ * C_ * K_ / 256), 256, 0, stream>>>(xcp, xsp, xch, xsh);
        x0_kernel<<<dim3(C_, B_), 256, 0, stream>>>(cur, wqn, x0h);
        f0_kernel<<<dim3(B_), C_, 0, stream>>>(x0h, w0, l, f0h);
        mix_kernel<<<dim3(K_ / 64, C_), 256, 0, stream>>>(xch, xsh, wc, ws, l,
                                                          fchh, fchl, fshh, fshl);
        inv_mfma<<<dim3(N_ / 32, B_), 256, 0, stream>>>(fchh, fchl, fshh, fshl,
            gxy, modes, cwh, cwl, hth, htl, f0h, conv_b, wqn, l,
            (l == L_ - 1) ? 1 : 0, nxt, hah, hal, hth, htl);
        float* t = cur; cur = nxt; nxt = t;
    }
    head_mfma<<<dim3(N_ / 32, B_), 256, 0, stream>>>(hth, htl, w1th, w1tl,
                                                     fc1_b, fc2_w, fc2_b, out);
}